// Round 1
// baseline (63773.682 us; speedup 1.0000x reference)
//
#include <hip/hip_runtime.h>

// PQMatcher persistent-kernel version.
// Previous round: 1282 dispatches (5 kernels x 256 steps) -> launch/drain
// overhead ~85us/step dominated the ~30us/step of real work.
// This round: ONE persistent kernel runs the whole 256-step scan with
// hand-rolled device-scope grid barriers (5 per step).
//   grid 256 blocks x 512 threads = 1 block/CU, 2 waves/SIMD,
//   __launch_bounds__(512,2) caps VGPR at 256 (vreg arrays are 128).
// Stage map per step p (all blocks participate in every stage):
//   S1: t = Wpf@up_p + Wv@v ; gh = W_hh@v + b_hh        (64 col-slices x 4 bgroups)
//   S2: s[b][q] = sum_h tanh(t+WUq)*Vvec                (2048 waves x 4 q each)
//   S3: softmax(s[b]) (redundant per block) + chalf=a@uq (8 blocks/b x 64 i)
//   S4: c_ = sig(Wg2f@[up|chalf]) * chalf               (64 slices x 4 bgroups)
//   S5: gi = W_ih@c_ + b_ih, GRU fused block-locally -> v, out[p]
// GRU fusion works because slice s computes gi rows {h, 1024+h, 2048+h : h in
// [16s,16s+16)} for its 8 b's -> GRU is elementwise in h, no global gi buffer.
// v single-buffered (same thread reads old, writes new). Weights keep a fixed
// block->slice mapping across steps -> L2-resident per XCD.

#define NB 32

__device__ __forceinline__ float fsig(float x) { return 1.0f / (1.0f + __expf(-x)); }
__device__ __forceinline__ float ftanh(float x) { return 1.0f - 2.0f / (1.0f + __expf(2.0f * x)); }

__device__ __forceinline__ float wred(float a) {
#pragma unroll
  for (int o = 32; o >= 1; o >>= 1) a += __shfl_xor(a, o, 64);
  return a;
}

// sense-reversing grid barrier: cnt/gen in workspace, zeroed by k_init each
// launch. Agent-scope atomics + __threadfence for cross-XCD visibility.
// Releaser resets cnt BEFORE release-storing gen, waiters acquire gen ->
// max skew 1 barrier, no cnt race.
__device__ __forceinline__ void gbar(int* cnt, int* gen) {
  __syncthreads();
  if (threadIdx.x == 0) {
    __threadfence();
    int g = __hip_atomic_load(gen, __ATOMIC_RELAXED, __HIP_MEMORY_SCOPE_AGENT);
    int a = __hip_atomic_fetch_add(cnt, 1, __ATOMIC_ACQ_REL, __HIP_MEMORY_SCOPE_AGENT);
    if (a == 255) {
      __hip_atomic_store(cnt, 0, __ATOMIC_RELAXED, __HIP_MEMORY_SCOPE_AGENT);
      __hip_atomic_store(gen, g + 1, __ATOMIC_RELEASE, __HIP_MEMORY_SCOPE_AGENT);
    } else {
      while (__hip_atomic_load(gen, __ATOMIC_ACQUIRE, __HIP_MEMORY_SCOPE_AGENT) == g)
        __builtin_amdgcn_s_sleep(2);
    }
    __threadfence();
  }
  __syncthreads();
}

// ---------------- init: barrier zero + folds + v0 copy ----------------
__global__ __launch_bounds__(256) void k_init(
    const float* __restrict__ v0, const float* __restrict__ Wp,
    const float* __restrict__ Wg, float* __restrict__ wsbase,
    float* __restrict__ vbuf, float* __restrict__ Wpf, float* __restrict__ Wg2f) {
  int i = blockIdx.x * 256 + threadIdx.x;
  if (i < 64) ((int*)wsbase)[i] = 0;
  if (i < NB * 1024) vbuf[i] = v0[i];
  if (i < 1024 * 512) {
    int n = i >> 9, k = i & 511;
    Wpf[i] = Wp[(size_t)n * 1024 + k] + Wp[(size_t)n * 1024 + k + 512];
  }
  if (i < 1024 * 1024) {
    int j = i >> 10, kk = i & 1023;
    const float* wr = Wg + (size_t)(1024 + j) * 2048;
    // r = [up, up, c, c]: fold duplicated K-halves
    Wg2f[i] = (kk < 512) ? (wr[kk] + wr[kk + 512]) : (wr[kk + 512] + wr[kk + 1024]);
  }
}

// ---------------- WUq = uq @ Wqf.T : [8192,512] x [512,1024] ----------------
__global__ __launch_bounds__(256) void k_wuq(
    const float* __restrict__ A, const float* __restrict__ Wq, float* __restrict__ C) {
  __shared__ float As[16][65];
  __shared__ float Bs[16][65];
  int bm = blockIdx.x * 64, bn = blockIdx.y * 64;
  int t = threadIdx.x;
  int tx = t & 15, ty = t >> 4;
  float acc[4][4] = {};
  for (int k0 = 0; k0 < 512; k0 += 16) {
#pragma unroll
    for (int l = 0; l < 4; ++l) {
      int idx = t + l * 256;
      int row = idx >> 4, kk = idx & 15;
      As[kk][row] = A[(size_t)(bm + row) * 512 + k0 + kk];
      Bs[kk][row] = Wq[(size_t)(bn + row) * 1024 + k0 + kk] +
                    Wq[(size_t)(bn + row) * 1024 + k0 + kk + 512];
    }
    __syncthreads();
#pragma unroll
    for (int kk = 0; kk < 16; ++kk) {
      float a0[4], b0[4];
#pragma unroll
      for (int i = 0; i < 4; ++i) a0[i] = As[kk][ty * 4 + i];
#pragma unroll
      for (int j = 0; j < 4; ++j) b0[j] = Bs[kk][tx * 4 + j];
#pragma unroll
      for (int i = 0; i < 4; ++i)
#pragma unroll
        for (int j = 0; j < 4; ++j) acc[i][j] += a0[i] * b0[j];
    }
    __syncthreads();
  }
#pragma unroll
  for (int i = 0; i < 4; ++i)
#pragma unroll
    for (int j = 0; j < 4; ++j)
      C[(size_t)(bm + ty * 4 + i) * 1024 + bn + tx * 4 + j] = acc[i][j];
}

// ---------------- the persistent 256-step scan ----------------
__global__ __launch_bounds__(512, 2) void k_loop(
    const float* __restrict__ up, const float* __restrict__ uq,
    const float* __restrict__ Vvec, const float* __restrict__ Wv,
    const float* __restrict__ W_hh, const float* __restrict__ b_hh,
    const float* __restrict__ W_ih, const float* __restrict__ b_ih,
    float* __restrict__ out, float* __restrict__ ws) {
  int* cnt = (int*)ws;
  int* gen = ((int*)ws) + 32;
  float* vbuf  = ws + 64;       // [32][1024]
  float* tbuf  = ws + 32832;    // [32][1024]
  float* ghbuf = ws + 65600;    // [32][3072]  (includes b_hh)
  float* sbuf  = ws + 163904;   // [32][256]
  float* chalf = ws + 172096;   // [32][512]
  float* cbuf  = ws + 188480;   // [32][1024]  (c_ = gated context)
  float* Wpf   = ws + 221248;   // [1024][512]
  float* Wg2f  = ws + 745536;   // [1024][1024]
  float* WUq   = ws + 1794112;  // [8192][1024]

  int bid = blockIdx.x;
  int tid = threadIdx.x, lane = tid & 63, wave = tid >> 6;

  __shared__ float smem[4096];  // 16KB: S1 up staging / S3 softmax / S5 gi

  int s = bid & 63, bg = bid >> 6, b0 = bg * 8;   // S1/S4/S5 mapping
  bool is_t = (s < 16);
  int b3 = bid >> 3, i0 = (bid & 7) * 64;         // S3 mapping

  for (int p = 0; p < 256; ++p) {
    // ================= S1: t = Wpf@up + Wv@v ; gh = W_hh@v + b_hh =========
    {
      float vreg[8][16];
#pragma unroll
      for (int bb = 0; bb < 8; ++bb)
#pragma unroll
        for (int i = 0; i < 16; ++i)
          vreg[bb][i] = vbuf[(size_t)(b0 + bb) * 1024 + lane + i * 64];
      if (is_t) {
        for (int idx = tid; idx < 4096; idx += 512) {
          int bb = idx >> 9, k = idx & 511;
          smem[idx] = up[((size_t)p * NB + b0 + bb) * 512 + k];
        }
      }
      __syncthreads();
      int n0 = s * 64 + wave * 8;
      for (int rr = 0; rr < 8; ++rr) {
        int n = n0 + rr;
        float acc[8];
#pragma unroll
        for (int bb = 0; bb < 8; ++bb) acc[bb] = 0.0f;
        if (is_t) {
          const float* wr = Wv + (size_t)n * 1024;
#pragma unroll
          for (int i = 0; i < 16; ++i) {
            float w = wr[lane + i * 64];
#pragma unroll
            for (int bb = 0; bb < 8; ++bb) acc[bb] = fmaf(w, vreg[bb][i], acc[bb]);
          }
          const float* wp = Wpf + (size_t)n * 512;
#pragma unroll
          for (int i = 0; i < 8; ++i) {
            float w = wp[lane + i * 64];
#pragma unroll
            for (int bb = 0; bb < 8; ++bb)
              acc[bb] = fmaf(w, smem[bb * 512 + lane + i * 64], acc[bb]);
          }
#pragma unroll
          for (int bb = 0; bb < 8; ++bb) {
            float a = wred(acc[bb]);
            if (lane == 0) tbuf[(size_t)(b0 + bb) * 1024 + n] = a;
          }
        } else {
          int m = n - 1024;
          const float* wr = W_hh + (size_t)m * 1024;
#pragma unroll
          for (int i = 0; i < 16; ++i) {
            float w = wr[lane + i * 64];
#pragma unroll
            for (int bb = 0; bb < 8; ++bb) acc[bb] = fmaf(w, vreg[bb][i], acc[bb]);
          }
          float bias = b_hh[m];
#pragma unroll
          for (int bb = 0; bb < 8; ++bb) {
            float a = wred(acc[bb]);
            if (lane == 0) ghbuf[(size_t)(b0 + bb) * 3072 + m] = a + bias;
          }
        }
      }
    }
    gbar(cnt, gen);

    // ================= S2: s[b][q] = sum_h tanh(t+WUq)*Vvec ================
    {
      int gw = bid * 8 + wave;          // 0..2047
      int b = gw & 31, q0 = (gw >> 5) * 4;
      float treg[16], vvreg[16];
#pragma unroll
      for (int i = 0; i < 16; ++i) {
        treg[i]  = tbuf[(size_t)b * 1024 + lane + i * 64];
        vvreg[i] = Vvec[(size_t)b * 1024 + lane + i * 64];
      }
      for (int qq = 0; qq < 4; ++qq) {
        int q = q0 + qq;
        const float* wu = WUq + ((size_t)q * NB + b) * 1024;
        float a = 0.0f;
#pragma unroll
        for (int i = 0; i < 16; ++i)
          a += ftanh(treg[i] + wu[lane + i * 64]) * vvreg[i];
        a = wred(a);
        if (lane == 0) sbuf[b * 256 + q] = a;
      }
    }
    gbar(cnt, gen);

    // ================= S3: softmax (per-block redundant) + chalf = a@uq ====
    {
      float* a_s  = smem;         // 256
      float* red  = smem + 256;   // 8
      float* part = smem + 512;   // 512
      int b = b3;
      float sv = -1e30f;
      if (tid < 256) sv = sbuf[b * 256 + tid];
      float m = sv;
#pragma unroll
      for (int o = 32; o >= 1; o >>= 1) m = fmaxf(m, __shfl_xor(m, o, 64));
      if (lane == 0 && wave < 4) red[wave] = m;
      __syncthreads();
      float bm = fmaxf(fmaxf(red[0], red[1]), fmaxf(red[2], red[3]));
      __syncthreads();
      float e = 0.0f;
      if (tid < 256) e = __expf(sv - bm);
      float se = e;
#pragma unroll
      for (int o = 32; o >= 1; o >>= 1) se += __shfl_xor(se, o, 64);
      if (lane == 0 && wave < 4) red[wave] = se;
      __syncthreads();
      float tot = red[0] + red[1] + red[2] + red[3];
      if (tid < 256) a_s[tid] = e / tot;
      __syncthreads();
      // chalf[b][i0+lane], wave w sums its 32 q's
      float acc = 0.0f;
      for (int qq = 0; qq < 32; ++qq) {
        int q = wave * 32 + qq;
        acc += a_s[q] * uq[((size_t)q * NB + b) * 512 + i0 + lane];
      }
      part[wave * 64 + lane] = acc;
      __syncthreads();
      if (tid < 64) {
        float c = 0.0f;
#pragma unroll
        for (int w = 0; w < 8; ++w) c += part[w * 64 + tid];
        chalf[(size_t)b * 512 + i0 + tid] = c;
      }
    }
    gbar(cnt, gen);

    // ================= S4: c_ = sig(Wg2f@[up|chalf]) * chalf ===============
    {
      float rreg[8][16];
#pragma unroll
      for (int bb = 0; bb < 8; ++bb) {
#pragma unroll
        for (int i = 0; i < 8; ++i)
          rreg[bb][i] = up[((size_t)p * NB + b0 + bb) * 512 + lane + i * 64];
#pragma unroll
        for (int i = 0; i < 8; ++i)
          rreg[bb][8 + i] = chalf[(size_t)(b0 + bb) * 512 + lane + i * 64];
      }
      int j0 = s * 16 + wave * 2;
      for (int rr = 0; rr < 2; ++rr) {
        int j = j0 + rr;
        const float* wr = Wg2f + (size_t)j * 1024;
        float acc[8];
#pragma unroll
        for (int bb = 0; bb < 8; ++bb) acc[bb] = 0.0f;
#pragma unroll
        for (int i = 0; i < 16; ++i) {
          float w = wr[lane + i * 64];
#pragma unroll
          for (int bb = 0; bb < 8; ++bb) acc[bb] = fmaf(w, rreg[bb][i], acc[bb]);
        }
#pragma unroll
        for (int bb = 0; bb < 8; ++bb) {
          float a = wred(acc[bb]);
          if (lane == 0) {
            float cv = chalf[(size_t)(b0 + bb) * 512 + (j & 511)];
            cbuf[(size_t)(b0 + bb) * 1024 + j] = fsig(a) * cv;
          }
        }
      }
    }
    gbar(cnt, gen);

    // ================= S5: gi = W_ih@c_ + b_ih, GRU fused -> v, out[p] =====
    {
      float creg[8][16];
#pragma unroll
      for (int bb = 0; bb < 8; ++bb)
#pragma unroll
        for (int i = 0; i < 16; ++i)
          creg[bb][i] = cbuf[(size_t)(b0 + bb) * 1024 + lane + i * 64];
      float* gi_s = smem;  // [48][8] = (g*16+ho)*8 + bb
      for (int k = 0; k < 6; ++k) {
        int idx = wave * 6 + k;          // 0..47
        int g = idx >> 4, ho = idx & 15;
        int r = g * 1024 + s * 16 + ho;
        const float* wr = W_ih + (size_t)r * 1024;
        float acc[8];
#pragma unroll
        for (int bb = 0; bb < 8; ++bb) acc[bb] = 0.0f;
#pragma unroll
        for (int i = 0; i < 16; ++i) {
          float w = wr[lane + i * 64];
#pragma unroll
          for (int bb = 0; bb < 8; ++bb) acc[bb] = fmaf(w, creg[bb][i], acc[bb]);
        }
        float bias = b_ih[r];
#pragma unroll
        for (int bb = 0; bb < 8; ++bb) {
          float a = wred(acc[bb]);
          if (lane == 0) gi_s[idx * 8 + bb] = a + bias;
        }
      }
      __syncthreads();
      if (tid < 128) {
        int ho = tid >> 3, bb = tid & 7;
        int h = s * 16 + ho, b = b0 + bb;
        const float* ghb = ghbuf + (size_t)b * 3072;
        float gir = gi_s[(0 * 16 + ho) * 8 + bb];
        float giz = gi_s[(1 * 16 + ho) * 8 + bb];
        float gin = gi_s[(2 * 16 + ho) * 8 + bb];
        float rg = fsig(gir + ghb[h]);
        float z  = fsig(giz + ghb[1024 + h]);
        float nn = ftanh(gin + rg * ghb[2048 + h]);
        float vo = vbuf[(size_t)b * 1024 + h];
        float vn = (1.0f - z) * nn + z * vo;
        vbuf[(size_t)b * 1024 + h] = vn;
        out[((size_t)p * NB + b) * 1024 + h] = vn;
      }
    }
    gbar(cnt, gen);
  }
}

extern "C" void kernel_launch(void* const* d_in, const int* in_sizes, int n_in,
                              void* d_out, int out_size, void* d_ws, size_t ws_size,
                              hipStream_t stream) {
  const float* up = (const float*)d_in[0];
  const float* uq = (const float*)d_in[1];
  const float* v0 = (const float*)d_in[2];
  const float* Vvec = (const float*)d_in[3];
  const float* Wp = (const float*)d_in[4];
  const float* Wq = (const float*)d_in[5];
  const float* Wv = (const float*)d_in[6];
  const float* Wg = (const float*)d_in[7];
  const float* W_ih = (const float*)d_in[8];
  const float* W_hh = (const float*)d_in[9];
  const float* b_ih = (const float*)d_in[10];
  const float* b_hh = (const float*)d_in[11];
  float* out = (float*)d_out;
  float* ws = (float*)d_ws;

  float* vbuf = ws + 64;
  float* Wpf  = ws + 221248;
  float* Wg2f = ws + 745536;
  float* WUq  = ws + 1794112;

  k_init<<<4096, 256, 0, stream>>>(v0, Wp, Wg, ws, vbuf, Wpf, Wg2f);
  k_wuq<<<dim3(128, 16), 256, 0, stream>>>(uq, Wq, WUq);
  // 256 blocks x 512 threads: exactly 1 block/CU (2048 waves << 8192 capacity)
  // -> all blocks co-resident, grid barrier is safe.
  k_loop<<<256, 512, 0, stream>>>(up, uq, Vvec, Wv, W_hh, b_hh, W_ih, b_ih, out, ws);
}

// Round 3
// 30351.382 us; speedup vs baseline: 2.1012x; 2.1012x over previous
//
#include <hip/hip_runtime.h>

// PQMatcher persistent-kernel, round 3.
// Round-1: acquire/release agent atomics in gbar -> buffer_inv sc1 per spin
//   poll -> L2 invalidate storm, VALUBusy 6%, 63.8ms.
// Round-2: relaxed sc1 everywhere (no cache maintenance) -> container failed
//   (infra flake OR stale-spin hang; cannot tell).
// Round-3 = round-2 hardened + LDS staging:
//  - gbar spin: relaxed polls with s_sleep; every 256th poll is an ACQUIRE
//    load (forces invalidate -> guaranteed freshness). Normal path (short
//    waits) never executes an acquire -> no invalidate traffic.
//  - All cross-stage intermediates (vbuf/tbuf/ghbuf/sbuf/chalf/cbuf) accessed
//    with RELAXED agent-scope atomics -> sc0 sc1 memops at the device-coherent
//    point, no buffer_inv/buffer_wbl2. Weights/WUq/uq/up stay plain cached.
//  - vbuf/chalf/cbuf staged into LDS once per block (was: every wave re-read
//    the same region via sc1 -> ~120MB/step memory-side; now ~25MB/step).
//  - v carried in registers by its S5 owner thread; out stores nontemporal.

#define NB 32

__device__ __forceinline__ float fsig(float x) { return 1.0f / (1.0f + __expf(-x)); }
__device__ __forceinline__ float ftanh(float x) { return 1.0f - 2.0f / (1.0f + __expf(2.0f * x)); }

__device__ __forceinline__ float wred(float a) {
#pragma unroll
  for (int o = 32; o >= 1; o >>= 1) a += __shfl_xor(a, o, 64);
  return a;
}

// coherent (device-scope) accessors: relaxed agent atomics -> sc0 sc1 memops,
// no cache-maintenance instructions.
__device__ __forceinline__ float cload(const float* p) {
  return __hip_atomic_load(p, __ATOMIC_RELAXED, __HIP_MEMORY_SCOPE_AGENT);
}
__device__ __forceinline__ void cstore(float* p, float v) {
  __hip_atomic_store(p, v, __ATOMIC_RELAXED, __HIP_MEMORY_SCOPE_AGENT);
}

// monotonic grid barrier: barrier k complete when cnt >= 256*k.
// __syncthreads() drains vmcnt per wave before s_barrier, so all sc1 stores
// are globally visible before the fetch_add. Spin is relaxed; every 256th
// poll is acquire (invalidate) as a freshness guarantee against stale lines.
__device__ __forceinline__ void gbar(int* cnt, int target) {
  __syncthreads();
  if (threadIdx.x == 0) {
    __hip_atomic_fetch_add(cnt, 1, __ATOMIC_RELAXED, __HIP_MEMORY_SCOPE_AGENT);
    int spins = 0;
    for (;;) {
      if (__hip_atomic_load(cnt, __ATOMIC_RELAXED, __HIP_MEMORY_SCOPE_AGENT) >= target) break;
      __builtin_amdgcn_s_sleep(8);
      if ((++spins & 255) == 0) {
        if (__hip_atomic_load(cnt, __ATOMIC_ACQUIRE, __HIP_MEMORY_SCOPE_AGENT) >= target) break;
      }
    }
  }
  __syncthreads();
}

// ---------------- init: barrier zero + folds + v0 copy ----------------
__global__ __launch_bounds__(256) void k_init(
    const float* __restrict__ v0, const float* __restrict__ Wp,
    const float* __restrict__ Wg, float* __restrict__ wsbase,
    float* __restrict__ vbuf, float* __restrict__ Wpf, float* __restrict__ Wg2f) {
  int i = blockIdx.x * 256 + threadIdx.x;
  if (i < 64) ((int*)wsbase)[i] = 0;
  if (i < NB * 1024) vbuf[i] = v0[i];
  if (i < 1024 * 512) {
    int n = i >> 9, k = i & 511;
    Wpf[i] = Wp[(size_t)n * 1024 + k] + Wp[(size_t)n * 1024 + k + 512];
  }
  if (i < 1024 * 1024) {
    int j = i >> 10, kk = i & 1023;
    const float* wr = Wg + (size_t)(1024 + j) * 2048;
    // r = [up, up, c, c]: fold duplicated K-halves
    Wg2f[i] = (kk < 512) ? (wr[kk] + wr[kk + 512]) : (wr[kk + 512] + wr[kk + 1024]);
  }
}

// ---------------- WUq = uq @ Wqf.T : [8192,512] x [512,1024] ----------------
__global__ __launch_bounds__(256) void k_wuq(
    const float* __restrict__ A, const float* __restrict__ Wq, float* __restrict__ C) {
  __shared__ float As[16][65];
  __shared__ float Bs[16][65];
  int bm = blockIdx.x * 64, bn = blockIdx.y * 64;
  int t = threadIdx.x;
  int tx = t & 15, ty = t >> 4;
  float acc[4][4] = {};
  for (int k0 = 0; k0 < 512; k0 += 16) {
#pragma unroll
    for (int l = 0; l < 4; ++l) {
      int idx = t + l * 256;
      int row = idx >> 4, kk = idx & 15;
      As[kk][row] = A[(size_t)(bm + row) * 512 + k0 + kk];
      Bs[kk][row] = Wq[(size_t)(bn + row) * 1024 + k0 + kk] +
                    Wq[(size_t)(bn + row) * 1024 + k0 + kk + 512];
    }
    __syncthreads();
#pragma unroll
    for (int kk = 0; kk < 16; ++kk) {
      float a0[4], b0[4];
#pragma unroll
      for (int i = 0; i < 4; ++i) a0[i] = As[kk][ty * 4 + i];
#pragma unroll
      for (int j = 0; j < 4; ++j) b0[j] = Bs[kk][tx * 4 + j];
#pragma unroll
      for (int i = 0; i < 4; ++i)
#pragma unroll
        for (int j = 0; j < 4; ++j) acc[i][j] += a0[i] * b0[j];
    }
    __syncthreads();
  }
#pragma unroll
  for (int i = 0; i < 4; ++i)
#pragma unroll
    for (int j = 0; j < 4; ++j)
      C[(size_t)(bm + ty * 4 + i) * 1024 + bn + tx * 4 + j] = acc[i][j];
}

// ---------------- the persistent 256-step scan ----------------
__global__ __launch_bounds__(512, 2) void k_loop(
    const float* __restrict__ up, const float* __restrict__ uq,
    const float* __restrict__ Vvec, const float* __restrict__ Wv,
    const float* __restrict__ W_hh, const float* __restrict__ b_hh,
    const float* __restrict__ W_ih, const float* __restrict__ b_ih,
    float* __restrict__ out, float* __restrict__ ws) {
  int* cnt = (int*)ws;
  float* vbuf  = ws + 64;       // [32][1024]
  float* tbuf  = ws + 32832;    // [32][1024]
  float* ghbuf = ws + 65600;    // [32][3072]  (includes b_hh)
  float* sbuf  = ws + 163904;   // [32][256]
  float* chalf = ws + 172096;   // [32][512]
  float* cbuf  = ws + 188480;   // [32][1024]  (c_ = gated context)
  float* Wpf   = ws + 221248;   // [1024][512]
  float* Wg2f  = ws + 745536;   // [1024][1024]
  float* WUq   = ws + 1794112;  // [8192][1024]

  int bid = blockIdx.x;
  int tid = threadIdx.x, lane = tid & 63, wave = tid >> 6;

  __shared__ float smem[12288];  // 48KB: [0..8191] v/c staging, [8192..] up/gi

  int s = bid & 63, bg = bid >> 6, b0 = bg * 8;   // S1/S4/S5 mapping
  bool is_t = (s < 16);
  int b3 = bid >> 3, i0 = (bid & 7) * 64;         // S3 mapping
  int b2 = bid & 31, qg2 = bid >> 5;              // S2 mapping

  // v element owned by this thread (S5 tail): one (b,h) per tid<128
  int ho5 = tid >> 3, bb5 = tid & 7;
  int h5 = s * 16 + ho5, b5 = b0 + bb5;
  float vloc = 0.0f;
  if (tid < 128) vloc = cload(vbuf + (size_t)b5 * 1024 + h5);

  int bar = 0;

  for (int p = 0; p < 256; ++p) {
    // ================= S1: t = Wpf@up + Wv@v ; gh = W_hh@v + b_hh =========
    {
      // stage this block's 8 b's of v (32KB) + up_p (16KB, t-blocks only)
      for (int idx = tid; idx < 8192; idx += 512)
        smem[idx] = cload(vbuf + (size_t)b0 * 1024 + idx);
      if (is_t) {
        for (int idx = tid; idx < 4096; idx += 512)
          smem[8192 + idx] = up[((size_t)p * NB + b0) * 512 + idx];
      }
      __syncthreads();
      float vreg[8][16];
#pragma unroll
      for (int bb = 0; bb < 8; ++bb)
#pragma unroll
        for (int i = 0; i < 16; ++i)
          vreg[bb][i] = smem[bb * 1024 + lane + i * 64];
      int n0 = s * 64 + wave * 8;
      for (int rr = 0; rr < 8; ++rr) {
        int n = n0 + rr;
        float acc[8];
#pragma unroll
        for (int bb = 0; bb < 8; ++bb) acc[bb] = 0.0f;
        if (is_t) {
          const float* wr = Wv + (size_t)n * 1024;
#pragma unroll
          for (int i = 0; i < 16; ++i) {
            float w = wr[lane + i * 64];
#pragma unroll
            for (int bb = 0; bb < 8; ++bb) acc[bb] = fmaf(w, vreg[bb][i], acc[bb]);
          }
          const float* wp = Wpf + (size_t)n * 512;
#pragma unroll
          for (int i = 0; i < 8; ++i) {
            float w = wp[lane + i * 64];
#pragma unroll
            for (int bb = 0; bb < 8; ++bb)
              acc[bb] = fmaf(w, smem[8192 + bb * 512 + lane + i * 64], acc[bb]);
          }
#pragma unroll
          for (int bb = 0; bb < 8; ++bb) {
            float a = wred(acc[bb]);
            if (lane == 0) cstore(tbuf + (size_t)(b0 + bb) * 1024 + n, a);
          }
        } else {
          int m = n - 1024;
          const float* wr = W_hh + (size_t)m * 1024;
#pragma unroll
          for (int i = 0; i < 16; ++i) {
            float w = wr[lane + i * 64];
#pragma unroll
            for (int bb = 0; bb < 8; ++bb) acc[bb] = fmaf(w, vreg[bb][i], acc[bb]);
          }
          float bias = b_hh[m];
#pragma unroll
          for (int bb = 0; bb < 8; ++bb) {
            float a = wred(acc[bb]);
            if (lane == 0) cstore(ghbuf + (size_t)(b0 + bb) * 3072 + m, a + bias);
          }
        }
      }
    }
    ++bar; gbar(cnt, 256 * bar);

    // ================= S2: s[b][q] = sum_h tanh(t+WUq)*Vvec ================
    // block handles b = bid&31, q = (bid>>5)*32 + wave*4 + qq.
    {
      for (int i = tid; i < 1024; i += 512)
        smem[i] = cload(tbuf + (size_t)b2 * 1024 + i);
      __syncthreads();
      float vvreg[16], treg[16];
#pragma unroll
      for (int i = 0; i < 16; ++i) {
        vvreg[i] = Vvec[(size_t)b2 * 1024 + lane + i * 64];
        treg[i] = smem[lane + i * 64];
      }
      for (int qq = 0; qq < 4; ++qq) {
        int q = qg2 * 32 + wave * 4 + qq;
        const float* wu = WUq + ((size_t)q * NB + b2) * 1024;
        float a = 0.0f;
#pragma unroll
        for (int i = 0; i < 16; ++i)
          a += ftanh(treg[i] + wu[lane + i * 64]) * vvreg[i];
        a = wred(a);
        if (lane == 0) cstore(sbuf + b2 * 256 + q, a);
      }
    }
    ++bar; gbar(cnt, 256 * bar);

    // ================= S3: softmax (per-block redundant) + chalf = a@uq ====
    {
      float* a_s  = smem;         // 256
      float* red  = smem + 256;   // 8
      float* part = smem + 512;   // 512
      int b = b3;
      float sv = -1e30f;
      if (tid < 256) sv = cload(sbuf + b * 256 + tid);
      float m = sv;
#pragma unroll
      for (int o = 32; o >= 1; o >>= 1) m = fmaxf(m, __shfl_xor(m, o, 64));
      if (lane == 0 && wave < 4) red[wave] = m;
      __syncthreads();
      float bm = fmaxf(fmaxf(red[0], red[1]), fmaxf(red[2], red[3]));
      __syncthreads();
      float e = 0.0f;
      if (tid < 256) e = __expf(sv - bm);
      float se = e;
#pragma unroll
      for (int o = 32; o >= 1; o >>= 1) se += __shfl_xor(se, o, 64);
      if (lane == 0 && wave < 4) red[wave] = se;
      __syncthreads();
      float tot = red[0] + red[1] + red[2] + red[3];
      if (tid < 256) a_s[tid] = e / tot;
      __syncthreads();
      // chalf[b][i0+lane], wave w sums its 32 q's
      float acc = 0.0f;
      for (int qq = 0; qq < 32; ++qq) {
        int q = wave * 32 + qq;
        acc += a_s[q] * uq[((size_t)q * NB + b) * 512 + i0 + lane];
      }
      part[wave * 64 + lane] = acc;
      __syncthreads();
      if (tid < 64) {
        float c = 0.0f;
#pragma unroll
        for (int w = 0; w < 8; ++w) c += part[w * 64 + tid];
        cstore(chalf + (size_t)b * 512 + i0 + tid, c);
      }
    }
    ++bar; gbar(cnt, 256 * bar);

    // ================= S4: c_ = sig(Wg2f@[up|chalf]) * chalf ===============
    {
      // stage this block's 8 b's of chalf (16KB)
      for (int idx = tid; idx < 4096; idx += 512)
        smem[idx] = cload(chalf + (size_t)b0 * 512 + idx);
      __syncthreads();
      float rreg[8][16];
#pragma unroll
      for (int bb = 0; bb < 8; ++bb) {
#pragma unroll
        for (int i = 0; i < 8; ++i)
          rreg[bb][i] = up[((size_t)p * NB + b0 + bb) * 512 + lane + i * 64];
#pragma unroll
        for (int i = 0; i < 8; ++i)
          rreg[bb][8 + i] = smem[bb * 512 + lane + i * 64];
      }
      int j0 = s * 16 + wave * 2;
      for (int rr = 0; rr < 2; ++rr) {
        int j = j0 + rr;
        const float* wr = Wg2f + (size_t)j * 1024;
        float acc[8];
#pragma unroll
        for (int bb = 0; bb < 8; ++bb) acc[bb] = 0.0f;
#pragma unroll
        for (int i = 0; i < 16; ++i) {
          float w = wr[lane + i * 64];
#pragma unroll
          for (int bb = 0; bb < 8; ++bb) acc[bb] = fmaf(w, rreg[bb][i], acc[bb]);
        }
#pragma unroll
        for (int bb = 0; bb < 8; ++bb) {
          float a = wred(acc[bb]);
          if (lane == 0) {
            float cv = smem[bb * 512 + (j & 511)];
            cstore(cbuf + (size_t)(b0 + bb) * 1024 + j, fsig(a) * cv);
          }
        }
      }
    }
    ++bar; gbar(cnt, 256 * bar);

    // ================= S5: gi = W_ih@c_ + b_ih, GRU fused -> v, out[p] =====
    {
      // prefetch gh for this thread's (b,h) early to hide sc1 latency
      float ghr = 0.0f, ghz = 0.0f, ghn = 0.0f;
      if (tid < 128) {
        const float* ghb = ghbuf + (size_t)b5 * 3072;
        ghr = cload(ghb + h5);
        ghz = cload(ghb + 1024 + h5);
        ghn = cload(ghb + 2048 + h5);
      }
      // stage this block's 8 b's of c_ (32KB)
      for (int idx = tid; idx < 8192; idx += 512)
        smem[idx] = cload(cbuf + (size_t)b0 * 1024 + idx);
      __syncthreads();
      float creg[8][16];
#pragma unroll
      for (int bb = 0; bb < 8; ++bb)
#pragma unroll
        for (int i = 0; i < 16; ++i)
          creg[bb][i] = smem[bb * 1024 + lane + i * 64];
      float* gi_s = smem + 8192;  // [48][8] = (g*16+ho)*8 + bb
      for (int k = 0; k < 6; ++k) {
        int idx = wave * 6 + k;          // 0..47
        int g = idx >> 4, ho = idx & 15;
        int r = g * 1024 + s * 16 + ho;
        const float* wr = W_ih + (size_t)r * 1024;
        float acc[8];
#pragma unroll
        for (int bb = 0; bb < 8; ++bb) acc[bb] = 0.0f;
#pragma unroll
        for (int i = 0; i < 16; ++i) {
          float w = wr[lane + i * 64];
#pragma unroll
          for (int bb = 0; bb < 8; ++bb) acc[bb] = fmaf(w, creg[bb][i], acc[bb]);
        }
        float bias = b_ih[r];
#pragma unroll
        for (int bb = 0; bb < 8; ++bb) {
          float a = wred(acc[bb]);
          if (lane == 0) gi_s[idx * 8 + bb] = a + bias;
        }
      }
      __syncthreads();
      if (tid < 128) {
        float gir = gi_s[(0 * 16 + ho5) * 8 + bb5];
        float giz = gi_s[(1 * 16 + ho5) * 8 + bb5];
        float gin = gi_s[(2 * 16 + ho5) * 8 + bb5];
        float rg = fsig(gir + ghr);
        float z  = fsig(giz + ghz);
        float nn = ftanh(gin + rg * ghn);
        float vn = (1.0f - z) * nn + z * vloc;
        vloc = vn;
        cstore(vbuf + (size_t)b5 * 1024 + h5, vn);
        __builtin_nontemporal_store(vn, out + ((size_t)p * NB + b5) * 1024 + h5);
      }
    }
    ++bar; gbar(cnt, 256 * bar);
  }
}

extern "C" void kernel_launch(void* const* d_in, const int* in_sizes, int n_in,
                              void* d_out, int out_size, void* d_ws, size_t ws_size,
                              hipStream_t stream) {
  const float* up = (const float*)d_in[0];
  const float* uq = (const float*)d_in[1];
  const float* v0 = (const float*)d_in[2];
  const float* Vvec = (const float*)d_in[3];
  const float* Wp = (const float*)d_in[4];
  const float* Wq = (const float*)d_in[5];
  const float* Wv = (const float*)d_in[6];
  const float* Wg = (const float*)d_in[7];
  const float* W_ih = (const float*)d_in[8];
  const float* W_hh = (const float*)d_in[9];
  const float* b_ih = (const float*)d_in[10];
  const float* b_hh = (const float*)d_in[11];
  float* out = (float*)d_out;
  float* ws = (float*)d_ws;

  float* vbuf = ws + 64;
  float* Wpf  = ws + 221248;
  float* Wg2f = ws + 745536;
  float* WUq  = ws + 1794112;

  k_init<<<4096, 256, 0, stream>>>(v0, Wp, Wg, ws, vbuf, Wpf, Wg2f);
  k_wuq<<<dim3(128, 16), 256, 0, stream>>>(uq, Wq, WUq);
  // 256 blocks x 512 threads, <=256 VGPR, 48KB LDS -> 1 block/CU, all 256
  // blocks co-resident -> grid barrier is safe.
  k_loop<<<256, 512, 0, stream>>>(up, uq, Vvec, Wv, W_hh, b_hh, W_ih, b_ih, out, ws);
}